// Round 6
// baseline (1064.819 us; speedup 1.0000x reference)
//
#include <hip/hip_runtime.h>
#include <hip/hip_bf16.h>

#define NN 20000
#define NE 320000
#define SLEN 548      // padded per-node accumulator stride (f32): 548%4==0, good banks
#define KTOT 544      // 16 basis blocks * 32 + 32 fc rows
#define NCH 17        // K chunks of 32

typedef __attribute__((ext_vector_type(8))) short short8;
typedef __attribute__((ext_vector_type(4))) float f32x4;

__device__ __forceinline__ unsigned short f2bf(float v) {
    unsigned u = __float_as_uint(v);
    unsigned r = (u + 0x7fffu + ((u >> 16) & 1u)) >> 16;
    return (unsigned short)r;
}
__device__ __forceinline__ float bf2f(unsigned short s) {
    return __uint_as_float(((unsigned)s) << 16);
}
__device__ __forceinline__ unsigned short f2h(float v) {
    union { _Float16 h; unsigned short u; } cv;
    cv.h = (_Float16)v;
    return cv.u;
}
__device__ __forceinline__ float h2f(unsigned short u) {
    union { unsigned short u; _Float16 h; } cv;
    cv.u = u;
    return (float)cv.h;
}

struct WPtrs { const float* cw[4]; const float* fw[4]; };

// ---- fused build: [0,1250) edge histogram; [1250,1563) cast feat->bf16 x0;
//      [1563,1597) build W2frag (pre-swizzled MFMA B-fragments, all 4 layers)
__global__ __launch_bounds__(256) void histprep_kernel(const int* __restrict__ ei,
                                                       int* __restrict__ counts,
                                                       WPtrs wp,
                                                       const float* __restrict__ feat,
                                                       unsigned short* __restrict__ x0,
                                                       unsigned short* __restrict__ w2frag) {
    int b = blockIdx.x, t = threadIdx.x;
    if (b < 1250) {
        int e = b * 256 + t;                     // 1250*256 == NE exactly
        atomicAdd(&counts[ei[e]], 1);
    } else if (b < 1563) {
        int idx = (b - 1250) * 256 + t;          // 80000 groups of 8 elems
        if (idx < 80000) {
            const float4* fsrc = (const float4*)(feat + (size_t)idx * 8);
            float4 a = fsrc[0], c = fsrc[1];
            short8 o;
            o[0] = (short)f2bf(a.x); o[1] = (short)f2bf(a.y);
            o[2] = (short)f2bf(a.z); o[3] = (short)f2bf(a.w);
            o[4] = (short)f2bf(c.x); o[5] = (short)f2bf(c.y);
            o[6] = (short)f2bf(c.z); o[7] = (short)f2bf(c.w);
            *(short8*)(x0 + (size_t)idx * 8) = o;
        }
    } else {
        int id2 = (b - 1563) * 256 + t;          // 4l * 2tile * 17c * 64lane = 8704
        if (id2 < 8704) {
            int lane = id2 & 63;
            int c = (id2 >> 6) % NCH;
            int lt = id2 / (NCH * 64);
            int l = lt >> 1, tt = lt & 1;
            int kb = (lane >> 4) * 8;
            int col = tt * 16 + (lane & 15);
            short8 o;
#pragma unroll
            for (int i = 0; i < 8; i++) {
                int k = c * 32 + kb + i;
                float v = (k < 512) ? wp.cw[l][(size_t)k * 32 + col]
                                    : wp.fw[l][(size_t)(k - 512) * 32 + col];
                o[i] = (short)f2bf(v);
            }
            *(short8*)(w2frag + (size_t)id2 * 8) = o;
        }
    }
}

// ---- CSR build: single-block scan, 20 elements/thread, fully unrolled
__global__ __launch_bounds__(1024) void scan_kernel(const int* __restrict__ counts,
                                                    int* __restrict__ rowst,
                                                    int* __restrict__ cursor) {
    __shared__ int s[1024];
    int t = threadIdx.x;
    int base = t * 20;
    int v[20];
    int sum = 0;
#pragma unroll
    for (int i = 0; i < 20; i++) {
        int idx = base + i;
        v[i] = (idx < NN) ? counts[idx] : 0;
        sum += v[i];
    }
    s[t] = sum;
    __syncthreads();
#pragma unroll
    for (int off = 1; off < 1024; off <<= 1) {
        int add = (t >= off) ? s[t - off] : 0;
        __syncthreads();
        s[t] += add;
        __syncthreads();
    }
    int run = s[t] - sum;
    if (t == 0) rowst[0] = 0;
#pragma unroll
    for (int i = 0; i < 20; i++) {
        int idx = base + i;
        if (idx < NN) {
            cursor[idx] = run;
            rowst[idx + 1] = run + v[i];
        }
        run += v[i];
    }
}

// ---- CSR fill + edge basis precompute (layer-invariant)
// emeta[p] = { j | bidx<<16, f16x2 w(dx=0;dy0 lo,dy1 hi), f16x2 w(dx=1), 0 }
__global__ __launch_bounds__(256) void fill_kernel(const int* __restrict__ ei,
                                                   const int* __restrict__ ej,
                                                   const float* __restrict__ attr,
                                                   int* __restrict__ cursor,
                                                   uint4* __restrict__ emeta) {
    int e = blockIdx.x * 256 + threadIdx.x;
    if (e >= NE) return;
    int i = ei[e], j = ej[e];
    int p = atomicAdd(&cursor[i], 1);
    float2 a = ((const float2*)attr)[e];
    float d0 = fminf(fmaxf(a.x, -1.f), 1.f);
    float d1 = fminf(fmaxf(a.y, -1.f), 1.f);
    float tx = (d0 + 1.f) * 1.5f;
    float ty = (d1 + 1.f) * 1.5f;
    int ix = min(2, max(0, (int)floorf(tx)));
    int iy = min(2, max(0, (int)floorf(ty)));
    float ux = tx - (float)ix;
    float uy = ty - (float)iy;
    float m = (i != j) ? 1.f : 0.f;   // centerIgnore
    unsigned w0 = (unsigned)f2h((1.f - ux) * (1.f - uy) * m)
                | ((unsigned)f2h((1.f - ux) * uy * m) << 16);
    unsigned w1 = (unsigned)f2h(ux * (1.f - uy) * m)
                | ((unsigned)f2h(ux * uy * m) << 16);
    uint4 mm;
    mm.x = (unsigned)j | ((unsigned)(ix * 4 + iy) << 16);
    mm.y = w0;
    mm.z = w1;
    mm.w = 0;
    emeta[p] = mm;
}

// ---- fused layer: 16 nodes/block, 1 wave/node.
// Phase A: scatter-accumulate s[node][b*32+fin] += w(dx,dy)*x_j[fin] in LDS (ds_add),
//          plus fc slot s[512..543] = x_i.
// Phase B: 2 MFMA waves compute ans[node][:] = S[node] . W2 (+bias, residual),
//          write ans f32 and x_next = bf16(relu(ans)); mode 2 -> scaled d_out.
__global__ __launch_bounds__(1024) void fused_kernel(const unsigned short* __restrict__ xin,
                                                     unsigned short* __restrict__ xout,
                                                     const uint4* __restrict__ emeta,
                                                     const int* __restrict__ rowst,
                                                     const unsigned short* __restrict__ w2frag,
                                                     const float* __restrict__ bias,
                                                     float* __restrict__ ansbuf,
                                                     float* __restrict__ outf,
                                                     int mode) {
    __shared__ float s[16][SLEN];
    int tid = threadIdx.x;
    int wv = tid >> 6, lane = tid & 63;
    for (int i = tid; i < 16 * SLEN; i += 1024) ((float*)s)[i] = 0.f;
    __syncthreads();

    int fp = lane & 15;
    int g = lane >> 4;                 // (dx,dy) group
    int dy = g & 1, dx = g >> 1;
    int fpr = (fp + g * 4) & 15;       // rotate features per group -> conflict-free ds_add
    int node = blockIdx.x * 16 + wv;
    int r0 = rowst[node], r1 = rowst[node + 1];
    float* srow = s[wv];

    if (r1 > r0) {
        int last = r1 - 1;
        uint4 mb[4];
#pragma unroll
        for (int k = 0; k < 4; k++) mb[k] = emeta[min(r0 + k, last)];
        for (int q = r0; q < r1; q += 4) {
            uint4 mc[4];
#pragma unroll
            for (int k = 0; k < 4; k++) mc[k] = mb[k];
            if (q + 4 < r1) {
#pragma unroll
                for (int k = 0; k < 4; k++) mb[k] = emeta[min(q + 4 + k, last)];
            }
            unsigned xv[4];
#pragma unroll
            for (int k = 0; k < 4; k++)
                xv[k] = *(const unsigned*)(xin + (size_t)(mc[k].x & 0xFFFF) * 32 + fpr * 2);
#pragma unroll
            for (int k = 0; k < 4; k++) {
                unsigned wb = dx ? mc[k].z : mc[k].y;
                float w = h2f((unsigned short)(dy ? (wb >> 16) : (wb & 0xFFFF)));
                w = (q + k < r1) ? w : 0.f;
                int bslot = (int)(mc[k].x >> 16) + (dx * 4 + dy);
                float xa = bf2f((unsigned short)(xv[k] & 0xFFFF));
                float xb = bf2f((unsigned short)(xv[k] >> 16));
                atomicAdd(&srow[bslot * 32 + fpr * 2], w * xa);
                atomicAdd(&srow[bslot * 32 + fpr * 2 + 1], w * xb);
            }
        }
    }
    if (g == 0) {   // fc slot: own features (fpr == fp here)
        unsigned xv = *(const unsigned*)(xin + (size_t)node * 32 + fp * 2);
        srow[512 + fp * 2] = bf2f((unsigned short)(xv & 0xFFFF));
        srow[512 + fp * 2 + 1] = bf2f((unsigned short)(xv >> 16));
    }
    __syncthreads();

    if (wv < 2) {
        int row = lane & 15;            // A-frag: node row
        int kb = (lane >> 4) * 8;
        const unsigned short* bp = w2frag + (size_t)wv * NCH * 512 + lane * 8;
        f32x4 acc = {0.f, 0.f, 0.f, 0.f};
#pragma unroll
        for (int c = 0; c < NCH; c++) {
            const float* ap = &s[row][c * 32 + kb];
            float4 a0 = *(const float4*)ap;
            float4 a1 = *(const float4*)(ap + 4);
            short8 av, bv;
            av[0] = (short)f2bf(a0.x); av[1] = (short)f2bf(a0.y);
            av[2] = (short)f2bf(a0.z); av[3] = (short)f2bf(a0.w);
            av[4] = (short)f2bf(a1.x); av[5] = (short)f2bf(a1.y);
            av[6] = (short)f2bf(a1.z); av[7] = (short)f2bf(a1.w);
            bv = *(const short8*)(bp + (size_t)c * 512);
            acc = __builtin_amdgcn_mfma_f32_16x16x32_bf16(av, bv, acc, 0, 0, 0);
        }
        int fo = wv * 16 + (lane & 15); // C/D: col=lane&15, row=(lane>>4)*4+r
        int nb = (lane >> 4) * 4;
        float bs = bias[fo];
#pragma unroll
        for (int r = 0; r < 4; r++) {
            int nd = blockIdx.x * 16 + nb + r;
            float val = acc[r] + bs;
            if (mode) val += ansbuf[(size_t)nd * 32 + fo];
            if (mode == 2) {
                outf[(size_t)nd * 32 + fo] = val * (1.f / 128.f);
            } else {
                ansbuf[(size_t)nd * 32 + fo] = val;
                xout[(size_t)nd * 32 + fo] = f2bf(fmaxf(val, 0.f));
            }
        }
    }
}

extern "C" void kernel_launch(void* const* d_in, const int* in_sizes, int n_in,
                              void* d_out, int out_size, void* d_ws, size_t ws_size,
                              hipStream_t stream) {
    const float* feat = (const float*)d_in[0];
    const int* ei = (const int*)d_in[1];
    const int* ej = (const int*)d_in[2];
    const float* attr = (const float*)d_in[3];
    WPtrs wp;
    const float* fcB[4];
    if (n_in >= 16) {
        for (int l = 0; l < 4; l++) {
            wp.cw[l] = (const float*)d_in[4 + l];
            wp.fw[l] = (const float*)d_in[8 + l];
            fcB[l]   = (const float*)d_in[12 + l];
        }
    } else {
        const float* cb = (const float*)d_in[4];
        const float* fb = (const float*)d_in[5];
        const float* bb = (const float*)d_in[6];
        for (int l = 0; l < 4; l++) {
            wp.cw[l] = cb + (size_t)l * 16 * 32 * 32;
            wp.fw[l] = fb + (size_t)l * 32 * 32;
            fcB[l]   = bb + (size_t)l * 32;
        }
    }

    char* p = (char*)d_ws;
    auto alloc = [&](size_t bytes) -> void* {
        void* r = (void*)p;
        p += (bytes + 255) & ~(size_t)255;
        return r;
    };
    unsigned short* w2frag = (unsigned short*)alloc((size_t)4 * 2 * NCH * 512 * sizeof(unsigned short));
    uint4* emeta  = (uint4*)alloc((size_t)NE * sizeof(uint4));
    int* counts   = (int*)alloc((size_t)NN * sizeof(int));
    int* cursor   = (int*)alloc((size_t)NN * sizeof(int));
    int* rowst    = (int*)alloc((size_t)(NN + 1) * sizeof(int));
    unsigned short* xA = (unsigned short*)alloc((size_t)NN * 32 * sizeof(unsigned short));
    unsigned short* xB = (unsigned short*)alloc((size_t)NN * 32 * sizeof(unsigned short));
    float* ans    = (float*)alloc((size_t)NN * 32 * sizeof(float));
    float* outf   = (float*)d_out;

    hipMemsetAsync(counts, 0, (size_t)NN * sizeof(int), stream);

    histprep_kernel<<<1597, 256, 0, stream>>>(ei, counts, wp, feat, xA, w2frag);
    scan_kernel<<<1, 1024, 0, stream>>>(counts, rowst, cursor);
    fill_kernel<<<(NE + 255) / 256, 256, 0, stream>>>(ei, ej, attr, cursor, emeta);

    size_t wl = (size_t)2 * NCH * 512;
    fused_kernel<<<NN / 16, 1024, 0, stream>>>(xA, xB, emeta, rowst, w2frag + 0 * wl,
                                               fcB[0], ans, outf, 0);
    fused_kernel<<<NN / 16, 1024, 0, stream>>>(xB, xA, emeta, rowst, w2frag + 1 * wl,
                                               fcB[1], ans, outf, 1);
    fused_kernel<<<NN / 16, 1024, 0, stream>>>(xA, xB, emeta, rowst, w2frag + 2 * wl,
                                               fcB[2], ans, outf, 1);
    fused_kernel<<<NN / 16, 1024, 0, stream>>>(xB, xA, emeta, rowst, w2frag + 3 * wl,
                                               fcB[3], ans, outf, 2);
}

// Round 7
// 207.270 us; speedup vs baseline: 5.1373x; 5.1373x over previous
//
#include <hip/hip_runtime.h>
#include <hip/hip_bf16.h>

#define NN 20000
#define NE 320000
#define NCH 17        // 16 conv slots + 1 fc slot, K chunks of 32
#define SROW 565      // per-node LDS row stride (floats): odd -> conflict-free
#define FCOFF 528     // 16*33: fc slot base within row

typedef __attribute__((ext_vector_type(8))) short short8;
typedef __attribute__((ext_vector_type(4))) float f32x4;

__device__ __forceinline__ unsigned short f2bf(float v) {
    unsigned u = __float_as_uint(v);
    unsigned r = (u + 0x7fffu + ((u >> 16) & 1u)) >> 16;
    return (unsigned short)r;
}
__device__ __forceinline__ float bf2f(unsigned short s) {
    return __uint_as_float(((unsigned)s) << 16);
}
__device__ __forceinline__ unsigned short f2h(float v) {
    union { _Float16 h; unsigned short u; } cv;
    cv.h = (_Float16)v;
    return cv.u;
}
__device__ __forceinline__ float h2f(unsigned short u) {
    union { unsigned short u; _Float16 h; } cv;
    cv.u = u;
    return (float)cv.h;
}

struct WPtrs { const float* cw[4]; const float* fw[4]; };

// ---- fused build: [0,1250) edge histogram; [1250,1563) cast feat->bf16 x0;
//      [1563,1597) build W2frag (pre-swizzled MFMA B-fragments, all 4 layers)
__global__ __launch_bounds__(256) void histprep_kernel(const int* __restrict__ ei,
                                                       int* __restrict__ counts,
                                                       WPtrs wp,
                                                       const float* __restrict__ feat,
                                                       unsigned short* __restrict__ x0,
                                                       unsigned short* __restrict__ w2frag) {
    int b = blockIdx.x, t = threadIdx.x;
    if (b < 1250) {
        int e = b * 256 + t;                     // 1250*256 == NE exactly
        atomicAdd(&counts[ei[e]], 1);
    } else if (b < 1563) {
        int idx = (b - 1250) * 256 + t;          // 80000 groups of 8 elems
        if (idx < 80000) {
            const float4* fsrc = (const float4*)(feat + (size_t)idx * 8);
            float4 a = fsrc[0], c = fsrc[1];
            short8 o;
            o[0] = (short)f2bf(a.x); o[1] = (short)f2bf(a.y);
            o[2] = (short)f2bf(a.z); o[3] = (short)f2bf(a.w);
            o[4] = (short)f2bf(c.x); o[5] = (short)f2bf(c.y);
            o[6] = (short)f2bf(c.z); o[7] = (short)f2bf(c.w);
            *(short8*)(x0 + (size_t)idx * 8) = o;
        }
    } else {
        int id2 = (b - 1563) * 256 + t;          // 4l * 2tile * 17c * 64lane = 8704
        if (id2 < 8704) {
            int lane = id2 & 63;
            int c = (id2 >> 6) % NCH;
            int lt = id2 / (NCH * 64);
            int l = lt >> 1, tt = lt & 1;
            int kb = (lane >> 4) * 8;
            int col = tt * 16 + (lane & 15);
            short8 o;
#pragma unroll
            for (int i = 0; i < 8; i++) {
                int k = c * 32 + kb + i;
                float v = (k < 512) ? wp.cw[l][(size_t)k * 32 + col]
                                    : wp.fw[l][(size_t)(k - 512) * 32 + col];
                o[i] = (short)f2bf(v);
            }
            *(short8*)(w2frag + (size_t)id2 * 8) = o;
        }
    }
}

// ---- CSR build: single-block scan, 20 elements/thread, fully unrolled
__global__ __launch_bounds__(1024) void scan_kernel(const int* __restrict__ counts,
                                                    int* __restrict__ rowst,
                                                    int* __restrict__ cursor) {
    __shared__ int s[1024];
    int t = threadIdx.x;
    int base = t * 20;
    int v[20];
    int sum = 0;
#pragma unroll
    for (int i = 0; i < 20; i++) {
        int idx = base + i;
        v[i] = (idx < NN) ? counts[idx] : 0;
        sum += v[i];
    }
    s[t] = sum;
    __syncthreads();
#pragma unroll
    for (int off = 1; off < 1024; off <<= 1) {
        int add = (t >= off) ? s[t - off] : 0;
        __syncthreads();
        s[t] += add;
        __syncthreads();
    }
    int run = s[t] - sum;
    if (t == 0) rowst[0] = 0;
#pragma unroll
    for (int i = 0; i < 20; i++) {
        int idx = base + i;
        if (idx < NN) {
            cursor[idx] = run;
            rowst[idx + 1] = run + v[i];
        }
        run += v[i];
    }
}

// ---- CSR fill + edge basis precompute (layer-invariant)
// ejb[p] = j | bb<<16 ; ew[p] = { f16x2 w(dx=0; dy0 lo, dy1 hi), f16x2 w(dx=1) }
__global__ __launch_bounds__(256) void fill_kernel(const int* __restrict__ ei,
                                                   const int* __restrict__ ej,
                                                   const float* __restrict__ attr,
                                                   int* __restrict__ cursor,
                                                   unsigned* __restrict__ ejb,
                                                   uint2* __restrict__ ew) {
    int e = blockIdx.x * 256 + threadIdx.x;
    if (e >= NE) return;
    int i = ei[e], j = ej[e];
    int p = atomicAdd(&cursor[i], 1);
    float2 a = ((const float2*)attr)[e];
    float d0 = fminf(fmaxf(a.x, -1.f), 1.f);
    float d1 = fminf(fmaxf(a.y, -1.f), 1.f);
    float tx = (d0 + 1.f) * 1.5f;
    float ty = (d1 + 1.f) * 1.5f;
    int ix = min(2, max(0, (int)floorf(tx)));
    int iy = min(2, max(0, (int)floorf(ty)));
    float ux = tx - (float)ix;
    float uy = ty - (float)iy;
    float m = (i != j) ? 1.f : 0.f;   // centerIgnore
    uint2 w;
    w.x = (unsigned)f2h((1.f - ux) * (1.f - uy) * m)
        | ((unsigned)f2h((1.f - ux) * uy * m) << 16);
    w.y = (unsigned)f2h(ux * (1.f - uy) * m)
        | ((unsigned)f2h(ux * uy * m) << 16);
    ejb[p] = (unsigned)j | ((unsigned)(ix * 4 + iy) << 16);
    ew[p] = w;
}

// ---- fused layer: 8 nodes/block, 1 wave/node.
// Phase A (atomic-free scatter): whole wave processes ONE edge per step.
// Lane (g,fp): slot = bb + {0,1,4,5}[g], feature-pair fp -> 64 distinct LDS
// addresses per step; sequential steps are ordered by the in-order LDS pipe.
// Phase B: waves 0,1 compute ans = S . W2 via MFMA (+bias/residual/relu).
__global__ __launch_bounds__(512, 6) void fused_kernel(const unsigned short* __restrict__ xin,
                                                       unsigned short* __restrict__ xout,
                                                       const unsigned* __restrict__ ejb,
                                                       const uint2* __restrict__ ew,
                                                       const int* __restrict__ rowst,
                                                       const unsigned short* __restrict__ w2frag,
                                                       const float* __restrict__ bias,
                                                       float* __restrict__ ansbuf,
                                                       float* __restrict__ outf,
                                                       int mode) {
    __shared__ float s[8][SROW];
    int tid = threadIdx.x;
    int wv = tid >> 6, lane = tid & 63;
    for (int i = tid; i < 8 * SROW; i += 512) ((float*)s)[i] = 0.f;
    __syncthreads();

    int fp = lane & 15;
    int g = lane >> 4;
    int dy = g & 1, dx = g >> 1;
    int soff = dx * 4 + dy;            // slot offset: {0,1,4,5}
    int node = blockIdx.x * 8 + wv;
    int r0 = rowst[node], r1 = rowst[node + 1];
    float* srow = s[wv];

    if (r1 > r0) {
        int last = r1 - 1;
        const unsigned* ewu = (const unsigned*)ew;
        unsigned ma[4], mb[4], wa[4], wb4[4], xa[4];
#pragma unroll
        for (int k = 0; k < 4; k++) ma[k] = ejb[min(r0 + k, last)];
#pragma unroll
        for (int k = 0; k < 4; k++) mb[k] = ejb[min(r0 + 4 + k, last)];
#pragma unroll
        for (int k = 0; k < 4; k++) wa[k] = ewu[(size_t)min(r0 + k, last) * 2 + dx];
#pragma unroll
        for (int k = 0; k < 4; k++) wb4[k] = ewu[(size_t)min(r0 + 4 + k, last) * 2 + dx];
#pragma unroll
        for (int k = 0; k < 4; k++)
            xa[k] = *(const unsigned*)(xin + (size_t)(ma[k] & 0xFFFF) * 32 + fp * 2);

        for (int q = r0; q < r1; q += 4) {
            unsigned mc[4], wc[4], xc[4];
#pragma unroll
            for (int k = 0; k < 4; k++) { mc[k] = ma[k]; wc[k] = wa[k]; xc[k] = xa[k]; }
#pragma unroll
            for (int k = 0; k < 4; k++) { ma[k] = mb[k]; wa[k] = wb4[k]; }
            if (q + 8 < r1) {
#pragma unroll
                for (int k = 0; k < 4; k++) mb[k] = ejb[min(q + 8 + k, last)];
#pragma unroll
                for (int k = 0; k < 4; k++) wb4[k] = ewu[(size_t)min(q + 8 + k, last) * 2 + dx];
            }
#pragma unroll
            for (int k = 0; k < 4; k++)
                xa[k] = *(const unsigned*)(xin + (size_t)(ma[k] & 0xFFFF) * 32 + fp * 2);
#pragma unroll
            for (int k = 0; k < 4; k++) {
                float w = h2f((unsigned short)(dy ? (wc[k] >> 16) : (wc[k] & 0xFFFF)));
                w = (q + k < r1) ? w : 0.f;
                int slot = (int)(mc[k] >> 16) + soff;
                int addr = slot * 33 + fp * 2;
                float xlo = bf2f((unsigned short)(xc[k] & 0xFFFF));
                float xhi = bf2f((unsigned short)(xc[k] >> 16));
                srow[addr]     += w * xlo;
                srow[addr + 1] += w * xhi;
            }
        }
    }
    if (g == 0) {   // fc slot: own features
        unsigned xv = *(const unsigned*)(xin + (size_t)node * 32 + fp * 2);
        srow[FCOFF + fp * 2]     = bf2f((unsigned short)(xv & 0xFFFF));
        srow[FCOFF + fp * 2 + 1] = bf2f((unsigned short)(xv >> 16));
    }
    __syncthreads();

    if (wv < 2) {
        int row = lane & 15;
        int arow = min(row, 7);
        int kb = (lane >> 4) * 8;
        const unsigned short* bp = w2frag + (size_t)wv * NCH * 512 + lane * 8;
        f32x4 acc = {0.f, 0.f, 0.f, 0.f};
#pragma unroll
        for (int c = 0; c < NCH; c++) {
            const float* ap = &s[arow][c * 33 + kb];
            short8 av, bv;
#pragma unroll
            for (int i = 0; i < 8; i++) {
                float fa = (row < 8) ? ap[i] : 0.f;
                av[i] = (short)f2bf(fa);
            }
            bv = *(const short8*)(bp + (size_t)c * 512);
            acc = __builtin_amdgcn_mfma_f32_16x16x32_bf16(av, bv, acc, 0, 0, 0);
        }
        int fo = wv * 16 + (lane & 15); // C/D: col=lane&15, row=(lane>>4)*4+r
        int nb = (lane >> 4) * 4;
        float bs = bias[fo];
#pragma unroll
        for (int r = 0; r < 4; r++) {
            int nrow = nb + r;
            if (nrow < 8) {
                int nd = blockIdx.x * 8 + nrow;
                float val = acc[r] + bs;
                if (mode) val += ansbuf[(size_t)nd * 32 + fo];
                if (mode == 2) {
                    outf[(size_t)nd * 32 + fo] = val * (1.f / 128.f);
                } else {
                    ansbuf[(size_t)nd * 32 + fo] = val;
                    xout[(size_t)nd * 32 + fo] = f2bf(fmaxf(val, 0.f));
                }
            }
        }
    }
}

extern "C" void kernel_launch(void* const* d_in, const int* in_sizes, int n_in,
                              void* d_out, int out_size, void* d_ws, size_t ws_size,
                              hipStream_t stream) {
    const float* feat = (const float*)d_in[0];
    const int* ei = (const int*)d_in[1];
    const int* ej = (const int*)d_in[2];
    const float* attr = (const float*)d_in[3];
    WPtrs wp;
    const float* fcB[4];
    if (n_in >= 16) {
        for (int l = 0; l < 4; l++) {
            wp.cw[l] = (const float*)d_in[4 + l];
            wp.fw[l] = (const float*)d_in[8 + l];
            fcB[l]   = (const float*)d_in[12 + l];
        }
    } else {
        const float* cb = (const float*)d_in[4];
        const float* fb = (const float*)d_in[5];
        const float* bb = (const float*)d_in[6];
        for (int l = 0; l < 4; l++) {
            wp.cw[l] = cb + (size_t)l * 16 * 32 * 32;
            wp.fw[l] = fb + (size_t)l * 32 * 32;
            fcB[l]   = bb + (size_t)l * 32;
        }
    }

    char* p = (char*)d_ws;
    auto alloc = [&](size_t bytes) -> void* {
        void* r = (void*)p;
        p += (bytes + 255) & ~(size_t)255;
        return r;
    };
    unsigned short* w2frag = (unsigned short*)alloc((size_t)4 * 2 * NCH * 512 * sizeof(unsigned short));
    unsigned* ejb = (unsigned*)alloc((size_t)NE * sizeof(unsigned));
    uint2* ew     = (uint2*)alloc((size_t)NE * sizeof(uint2));
    int* counts   = (int*)alloc((size_t)NN * sizeof(int));
    int* cursor   = (int*)alloc((size_t)NN * sizeof(int));
    int* rowst    = (int*)alloc((size_t)(NN + 1) * sizeof(int));
    unsigned short* xA = (unsigned short*)alloc((size_t)NN * 32 * sizeof(unsigned short));
    unsigned short* xB = (unsigned short*)alloc((size_t)NN * 32 * sizeof(unsigned short));
    float* ans    = (float*)alloc((size_t)NN * 32 * sizeof(float));
    float* outf   = (float*)d_out;

    hipMemsetAsync(counts, 0, (size_t)NN * sizeof(int), stream);

    histprep_kernel<<<1597, 256, 0, stream>>>(ei, counts, wp, feat, xA, w2frag);
    scan_kernel<<<1, 1024, 0, stream>>>(counts, rowst, cursor);
    fill_kernel<<<(NE + 255) / 256, 256, 0, stream>>>(ei, ej, attr, cursor, ejb, ew);

    size_t wl = (size_t)2 * NCH * 512;
    fused_kernel<<<NN / 8, 512, 0, stream>>>(xA, xB, ejb, ew, rowst, w2frag + 0 * wl,
                                             fcB[0], ans, outf, 0);
    fused_kernel<<<NN / 8, 512, 0, stream>>>(xB, xA, ejb, ew, rowst, w2frag + 1 * wl,
                                             fcB[1], ans, outf, 1);
    fused_kernel<<<NN / 8, 512, 0, stream>>>(xA, xB, ejb, ew, rowst, w2frag + 2 * wl,
                                             fcB[2], ans, outf, 1);
    fused_kernel<<<NN / 8, 512, 0, stream>>>(xB, xA, ejb, ew, rowst, w2frag + 3 * wl,
                                             fcB[3], ans, outf, 2);
}